// Round 5
// baseline (60.680 us; speedup 1.0000x reference)
//
#include <hip/hip_runtime.h>
#include <math.h>

#define NLEV 3
#define BATCH 16
#define NGT 32
#define NCLS 80
#define NA 3

// positions per level = B*A*H*W
#define P0 307200
#define P1 76800
#define P2 19200

// obj: 2048 positions per block (256 threads x 8)
#define OBJ_NB0 150            // P0 / 2048
#define OBJ_NB1 38             // ceil(P1 / 2048)
#define OBJ_NB2 10             // ceil(P2 / 2048)
#define OBJ_NB  (OBJ_NB0 + OBJ_NB1 + OBJ_NB2)   // 198
#define OBJ_B0  OBJ_NB0                          // 150
#define OBJ_B01 (OBJ_NB0 + OBJ_NB1)              // 188

#define NASSIGN (BATCH * NLEV)  // 48
#define NB (NASSIGN + OBJ_NB)   // 246 blocks <= 256 CUs: single round

// ws layout (floats):
// [0 .. OBJ_NB)            per-obj-block softplus partial sums
// [4096 + aid*4 .. +4)     per-(b,lev) partials: {sum obj_p@pos, sum boxsq, sum cls, npos}
#define ASSIGN_OFF 4096

// analytic anchors (from reference ANCHOR_SIZES; grid center = (i+0.5)*stride, exact in f32)
__constant__ const float c_AW[NLEV][NA] = {{12.f, 19.f, 40.f}, {36.f, 76.f, 72.f}, {142.f, 192.f, 459.f}};
__constant__ const float c_AH[NLEV][NA] = {{16.f, 36.f, 28.f}, {75.f, 55.f, 146.f}, {110.f, 243.f, 401.f}};

__device__ __forceinline__ float softplusf(float x) {
    // stable log(1+exp(x)) == max(x,0) + log1p(exp(-|x|))
    return fmaxf(x, 0.0f) + log1pf(expf(-fabsf(x)));
}

__global__ void fused_kernel(const float* __restrict__ p0, const float* __restrict__ p1,
                             const float* __restrict__ p2,
                             const float* __restrict__ gtb, const int* __restrict__ gtl,
                             float* __restrict__ ws) {
    const int blk = blockIdx.x;
    const int tid = threadIdx.x;
    const int wid = tid >> 6, lane = tid & 63;

    __shared__ float wsum[4];
    __shared__ int      s_key[NGT];
    __shared__ float    s_iou[NGT];
    __shared__ unsigned s_off[NGT];      // element offset into pred, 0xFFFFFFFF = not chosen
    __shared__ float    s_t[NGT][4];
    __shared__ int      s_lab[NGT];
    __shared__ float    s_np;
    __shared__ float    s_red[4][3];

    if (blk >= NASSIGN) {
        // ---- obj duty: softplus over obj logits, 8 positions per thread, loads hoisted ----
        const int ob = blk - NASSIGN;
        const float* p;
        int base, plim;
        if (ob < OBJ_B0)       { p = p0; base = ob * 2048;               plim = P0; }
        else if (ob < OBJ_B01) { p = p1; base = (ob - OBJ_B0) * 2048;    plim = P1; }
        else                   { p = p2; base = (ob - OBJ_B01) * 2048;   plim = P2; }

        float x[8];
        #pragma unroll
        for (int k = 0; k < 8; ++k) {
            const int pos = base + k * 256 + tid;
            x[k] = (pos < plim) ? p[(size_t)pos * (5 + NCLS) + 4] : 0.0f;
        }
        float v = 0.0f;
        #pragma unroll
        for (int k = 0; k < 8; ++k) {
            const int pos = base + k * 256 + tid;
            if (pos < plim) v += softplusf(x[k]);
        }
        for (int off = 32; off > 0; off >>= 1) v += __shfl_down(v, off);
        if (lane == 0) wsum[wid] = v;
        __syncthreads();
        if (tid == 0) ws[ob] = wsum[0] + wsum[1] + wsum[2] + wsum[3];
        return;
    }

    // ---- assign duty: one block per (b, lev); anchors computed analytically ----
    const int aid = blk;
    const int lev = aid % NLEV;
    const int b   = aid / NLEV;

    const int Hs[NLEV]     = {80, 40, 20};
    const float strd[NLEV] = {8.0f, 16.0f, 32.0f};
    const float* pred = (lev == 0) ? p0 : ((lev == 1) ? p1 : p2);
    const int H = Hs[lev], W = Hs[lev];
    const int HW = H * W;
    const float stride = strd[lev];
    // block-uniform anchor sizes (SGPR)
    const float aw0 = c_AW[lev][0], aw1 = c_AW[lev][1], aw2 = c_AW[lev][2];
    const float ah0 = c_AH[lev][0], ah1 = c_AH[lev][1], ah2 = c_AH[lev][2];

    // stage 1a: per-GT best anchor (lanes 0..31 of wave 0) — single coalesced load, rest ALU
    float x1 = 0.f, y1 = 0.f, x2 = 0.f, y2 = 0.f, cx = 0.f, cy = 0.f;
    float acx = 0.f, acy = 0.f;
    float biou = -1.0f;
    int ba = 0, gx = 0, gy = 0, key = -1, lab = 0;

    if (tid < NGT) {
        const float4 g = ((const float4*)gtb)[b * NGT + tid];
        lab = gtl[b * NGT + tid];
        x1 = g.x; y1 = g.y; x2 = g.z; y2 = g.w;
        cx = (x1 + x2) * 0.5f;
        cy = (y1 + y2) * 0.5f;
        gx = (int)(cx / stride); gx = gx < 0 ? 0 : (gx > W - 1 ? W - 1 : gx);
        gy = (int)(cy / stride); gy = gy < 0 ? 0 : (gy > H - 1 ? H - 1 : gy);
        acx = ((float)gx + 0.5f) * stride;
        acy = ((float)gy + 0.5f) * stride;
        const float area1 = (x2 - x1) * (y2 - y1);
        #pragma unroll
        for (int aa = 0; aa < NA; ++aa) {
            const float aw = (aa == 0) ? aw0 : ((aa == 1) ? aw1 : aw2);
            const float ah = (aa == 0) ? ah0 : ((aa == 1) ? ah1 : ah2);
            const float c1x = acx - aw * 0.5f, c1y = acy - ah * 0.5f;
            const float c2x = acx + aw * 0.5f, c2y = acy + ah * 0.5f;
            const float ltx = fmaxf(x1, c1x), lty = fmaxf(y1, c1y);
            const float rbx = fminf(x2, c2x), rby = fminf(y2, c2y);
            const float wx = fmaxf(rbx - ltx, 0.0f), wy = fmaxf(rby - lty, 0.0f);
            const float inter = wx * wy;
            const float iou = inter / (area1 + aw * ah - inter + 1e-16f);
            if (iou > biou) { biou = iou; ba = aa; }   // strict > keeps first max (jnp.argmax)
        }
        key = ba * HW + gy * W + gx;
        s_key[tid] = key;
        s_iou[tid] = biou;
    }
    __syncthreads();

    // stage 1b: winner resolution + target precompute (lanes 0..31 of wave 0) — no loads
    if (tid < NGT) {
        bool chosen = true;
        for (int m = 0; m < NGT; ++m) {
            if (m == tid) continue;
            if (s_key[m] == key) {
                const float im = s_iou[m];
                if (im > biou || (im == biou && m < tid)) chosen = false;
            }
        }
        if (chosen) {
            const float aw = (ba == 0) ? aw0 : ((ba == 1) ? aw1 : aw2);
            const float ah = (ba == 0) ? ah0 : ((ba == 1) ? ah1 : ah2);
            s_t[tid][0] = (cx - acx) * 0.125f;   // / STRIDES[0] = 8
            s_t[tid][1] = (cy - acy) * 0.125f;
            s_t[tid][2] = logf((x2 - x1) / aw + 1e-16f);
            s_t[tid][3] = logf((y2 - y1) / ah + 1e-16f);
            s_lab[tid]  = lab;
            s_off[tid]  = (unsigned)(((b * NA + ba) * HW + gy * W + gx) * (5 + NCLS));
        } else {
            s_off[tid] = 0xFFFFFFFFu;
        }
        const unsigned long long mm = __ballot(chosen);
        if (tid == 0) s_np = (float)__popcll(mm);
    }
    __syncthreads();

    // stage 2: wave w handles GTs [w*8, w*8+8); ALL 16 loads hoisted into one burst.
    unsigned offs[8];
    int      labs[8];
    #pragma unroll
    for (int g8 = 0; g8 < 8; ++g8) {
        offs[g8] = s_off[wid * 8 + g8];
        labs[g8] = s_lab[wid * 8 + g8];
    }
    float v0[8], v1[8];
    #pragma unroll
    for (int g8 = 0; g8 < 8; ++g8) {
        // unconditional loads (dummy offset 0 for non-chosen: always valid memory)
        const unsigned off = (offs[g8] == 0xFFFFFFFFu) ? 0u : offs[g8];
        const float* f = pred + off;
        v0[g8] = f[lane];
        v1[g8] = (lane < 21) ? f[lane + 64] : 0.0f;
    }

    float accO = 0.f, accB = 0.f, accC = 0.f;
    #pragma unroll
    for (int g8 = 0; g8 < 8; ++g8) {
        if (offs[g8] == 0xFFFFFFFFu) continue;
        const int glab = labs[g8];
        const float a = v0[g8];
        if (lane < 4) {
            const float d = a - s_t[wid * 8 + g8][lane];
            accB += d * d;
        } else if (lane == 4) {
            accO += a;
        } else {
            accC += softplusf(a);
            if (lane - 5 == glab) accC -= a;
        }
        if (lane < 21) {
            const float c = v1[g8];
            accC += softplusf(c);
            if (lane + 59 == glab) accC -= c;
        }
    }

    for (int off = 32; off > 0; off >>= 1) {
        accO += __shfl_down(accO, off);
        accB += __shfl_down(accB, off);
        accC += __shfl_down(accC, off);
    }
    if (lane == 0) { s_red[wid][0] = accO; s_red[wid][1] = accB; s_red[wid][2] = accC; }
    __syncthreads();
    if (tid == 0) {
        float* dst = ws + ASSIGN_OFF + (size_t)aid * 4;
        dst[0] = s_red[0][0] + s_red[1][0] + s_red[2][0] + s_red[3][0];
        dst[1] = s_red[0][1] + s_red[1][1] + s_red[2][1] + s_red[3][1];
        dst[2] = s_red[0][2] + s_red[1][2] + s_red[2][2] + s_red[3][2];
        dst[3] = s_np;
    }
}

__global__ void finalize_kernel(const float* __restrict__ ws, float* __restrict__ out) {
    const int tid = threadIdx.x;
    const int lane = tid & 63, wid = tid >> 6;

    // reduce obj partials into per-level sums (198 entries)
    float a0 = 0.f, a1 = 0.f, a2 = 0.f;
    for (int i = tid; i < OBJ_NB; i += 256) {
        const float v = ws[i];
        if (i < OBJ_B0)       a0 += v;
        else if (i < OBJ_B01) a1 += v;
        else                  a2 += v;
    }
    for (int off = 32; off > 0; off >>= 1) {
        a0 += __shfl_down(a0, off);
        a1 += __shfl_down(a1, off);
        a2 += __shfl_down(a2, off);
    }
    __shared__ float red[4][3];
    if (lane == 0) { red[wid][0] = a0; red[wid][1] = a1; red[wid][2] = a2; }

    // reduce assign partials wave-parallel (wave 1: lane g < 48 owns record g)
    __shared__ float ared[4][NLEV];   // {po, bx, cl, np} x level
    if (wid == 1) {
        float po = 0.f, bx = 0.f, cl = 0.f, np = 0.f;
        int l = 0;
        if (lane < NASSIGN) {
            const float* src = ws + ASSIGN_OFF + (size_t)lane * 4;
            po = src[0]; bx = src[1]; cl = src[2]; np = src[3];
            l = lane % NLEV;
        }
        for (int lv = 0; lv < NLEV; ++lv) {
            float vpo = (l == lv && lane < NASSIGN) ? po : 0.f;
            float vbx = (l == lv && lane < NASSIGN) ? bx : 0.f;
            float vcl = (l == lv && lane < NASSIGN) ? cl : 0.f;
            float vnp = (l == lv && lane < NASSIGN) ? np : 0.f;
            for (int off = 32; off > 0; off >>= 1) {
                vpo += __shfl_down(vpo, off);
                vbx += __shfl_down(vbx, off);
                vcl += __shfl_down(vcl, off);
                vnp += __shfl_down(vnp, off);
            }
            if (lane == 0) { ared[0][lv] = vpo; ared[1][lv] = vbx; ared[2][lv] = vcl; ared[3][lv] = vnp; }
        }
    }
    __syncthreads();

    if (tid == 0) {
        const float BKs[NLEV] = {(float)P0, (float)P1, (float)P2};
        float tb = 0.f, to = 0.f, tc = 0.f, tot = 0.f;
        for (int l = 0; l < NLEV; ++l) {
            const float sp = red[0][l] + red[1][l] + red[2][l] + red[3][l];
            const float po = ared[0][l], bx = ared[1][l], cl = ared[2][l], np = ared[3][l];
            const float denom = fmaxf(np, 1.0f);
            const float obj_l = (sp - po) / BKs[l];
            const float box_l = bx / denom;
            const float cls_l = cl / (denom * (float)NCLS);
            if (np > 0.f) { tb += box_l; tc += cls_l; }
            to += obj_l;
            tot += np;
        }
        if (tot > 0.f) { tb /= 3.0f; tc /= 3.0f; } else { tb = 0.f; tc = 0.f; }
        to /= 3.0f;
        out[0] = 0.05f * tb + 1.0f * to + 0.5f * tc;
    }
}

extern "C" void kernel_launch(void* const* d_in, const int* in_sizes, int n_in,
                              void* d_out, int out_size, void* d_ws, size_t ws_size,
                              hipStream_t stream) {
    // defensive pointer mapping by element count (all sizes distinct)
    const float* p[3] = {nullptr, nullptr, nullptr};
    const float* gtb = nullptr;
    const int*   gtl = nullptr;
    for (int i = 0; i < n_in; ++i) {
        switch (in_sizes[i]) {
            case 26112000: p[0] = (const float*)d_in[i]; break;
            case 6528000:  p[1] = (const float*)d_in[i]; break;
            case 1632000:  p[2] = (const float*)d_in[i]; break;
            case 2048:     gtb  = (const float*)d_in[i]; break;
            case 512:      gtl  = (const int*)d_in[i];   break;
            default: break;
        }
    }
    if (!p[0]) p[0] = (const float*)d_in[0];
    if (!p[1]) p[1] = (const float*)d_in[2];
    if (!p[2]) p[2] = (const float*)d_in[4];
    if (!gtb)  gtb  = (const float*)d_in[6];
    if (!gtl)  gtl  = (const int*)d_in[7];

    float* ws = (float*)d_ws;

    fused_kernel<<<NB, 256, 0, stream>>>(p[0], p[1], p[2], gtb, gtl, ws);
    finalize_kernel<<<1, 256, 0, stream>>>(ws, (float*)d_out);
}

// Round 6
// 23.477 us; speedup vs baseline: 2.5846x; 2.5846x over previous
//
#include <hip/hip_runtime.h>
#include <math.h>

#define NLEV 3
#define BATCH 16
#define NGT 32
#define NCLS 80
#define NA 3

// positions per level = B*A*H*W
#define P0 307200
#define P1 76800
#define P2 19200

// obj: 1024 positions per block (256 threads x 4)
#define OBJ_NB0 300            // P0 / 1024
#define OBJ_NB1 75             // P1 / 1024
#define OBJ_NB2 19             // ceil(P2 / 1024)
#define OBJ_NB  (OBJ_NB0 + OBJ_NB1 + OBJ_NB2)   // 394
#define OBJ_B0  OBJ_NB0
#define OBJ_B01 (OBJ_NB0 + OBJ_NB1)             // 375

#define NASSIGN (BATCH * NLEV)  // 48
#define NB (NASSIGN + OBJ_NB)   // 442; assign blocks FIRST (longest dep chain)

// ws layout (floats):
// [0 .. OBJ_NB)            per-obj-block softplus partial sums
// [4096 + aid*4 .. +4)     per-(b,lev) partials: {sum obj_p@pos, sum boxsq, sum cls, npos}
#define ASSIGN_OFF 4096

__device__ __forceinline__ float softplusf(float x) {
    // stable log(1+exp(x)) == max(x,0) + log1p(exp(-|x|))
    return fmaxf(x, 0.0f) + log1pf(expf(-fabsf(x)));
}

__global__ void fused_kernel(const float* __restrict__ p0, const float* __restrict__ p1,
                             const float* __restrict__ p2,
                             const float* __restrict__ gtb, const int* __restrict__ gtl,
                             float* __restrict__ ws) {
    const int blk = blockIdx.x;
    const int tid = threadIdx.x;
    const int wid = tid >> 6, lane = tid & 63;

    __shared__ float wsum[4];
    __shared__ int      s_key[NGT];
    __shared__ float    s_iou[NGT];
    __shared__ unsigned s_off[NGT];      // element offset into pred, 0xFFFFFFFF = not chosen
    __shared__ float    s_t[NGT][4];
    __shared__ int      s_lab[NGT];
    __shared__ float    s_np;
    __shared__ float    s_red[4][3];

    if (blk >= NASSIGN) {
        // ---- obj duty: softplus over obj logits, 4 positions per thread ----
        const int ob = blk - NASSIGN;
        const float* p;
        int base, plim;
        if (ob < OBJ_NB0)      { p = p0; base = ob * 1024;               plim = P0; }
        else if (ob < OBJ_B01) { p = p1; base = (ob - OBJ_NB0) * 1024;   plim = P1; }
        else                   { p = p2; base = (ob - OBJ_B01) * 1024;   plim = P2; }

        float v = 0.0f;
        #pragma unroll
        for (int k = 0; k < 4; ++k) {
            const int pos = base + k * 256 + tid;
            if (pos < plim) v += softplusf(p[(size_t)pos * (5 + NCLS) + 4]);
        }
        for (int off = 32; off > 0; off >>= 1) v += __shfl_down(v, off);
        if (lane == 0) wsum[wid] = v;
        __syncthreads();
        if (tid == 0) ws[ob] = wsum[0] + wsum[1] + wsum[2] + wsum[3];
        return;
    }

    // ---- assign duty: one block per (b, lev); anchors computed analytically ----
    const int aid = blk;
    const int lev = aid % NLEV;
    const int b   = aid / NLEV;

    // block-uniform level params via select chains (no runtime-indexed arrays -> no scratch)
    const float* pred = (lev == 0) ? p0 : ((lev == 1) ? p1 : p2);
    const int   W      = (lev == 0) ? 80 : ((lev == 1) ? 40 : 20);
    const float stride = (lev == 0) ? 8.0f : ((lev == 1) ? 16.0f : 32.0f);
    const int H = W;
    const int HW = H * W;
    // anchor sizes per level (reference ANCHOR_SIZES), compile-time constants selected by lev
    const float aw0 = (lev == 0) ? 12.f  : ((lev == 1) ? 36.f : 142.f);
    const float ah0 = (lev == 0) ? 16.f  : ((lev == 1) ? 75.f : 110.f);
    const float aw1 = (lev == 0) ? 19.f  : ((lev == 1) ? 76.f : 192.f);
    const float ah1 = (lev == 0) ? 36.f  : ((lev == 1) ? 55.f : 243.f);
    const float aw2 = (lev == 0) ? 40.f  : ((lev == 1) ? 72.f : 459.f);
    const float ah2 = (lev == 0) ? 28.f  : ((lev == 1) ? 146.f : 401.f);

    // stage 1a: per-GT best anchor (lanes 0..31 of wave 0) — one coalesced float4 load, rest ALU
    float x1 = 0.f, y1 = 0.f, x2 = 0.f, y2 = 0.f, cx = 0.f, cy = 0.f;
    float acx = 0.f, acy = 0.f;
    float biou = -1.0f;
    int ba = 0, gx = 0, gy = 0, key = -1, lab = 0;

    if (tid < NGT) {
        const float4 g = ((const float4*)gtb)[b * NGT + tid];
        lab = gtl[b * NGT + tid];          // independent load, issues in parallel
        x1 = g.x; y1 = g.y; x2 = g.z; y2 = g.w;
        cx = (x1 + x2) * 0.5f;
        cy = (y1 + y2) * 0.5f;
        gx = (int)(cx / stride); gx = gx < 0 ? 0 : (gx > W - 1 ? W - 1 : gx);
        gy = (int)(cy / stride); gy = gy < 0 ? 0 : (gy > H - 1 ? H - 1 : gy);
        acx = ((float)gx + 0.5f) * stride;   // grid centers exact in f32 (stride pow2)
        acy = ((float)gy + 0.5f) * stride;
        const float area1 = (x2 - x1) * (y2 - y1);
        #pragma unroll
        for (int aa = 0; aa < NA; ++aa) {
            const float aw = (aa == 0) ? aw0 : ((aa == 1) ? aw1 : aw2);
            const float ah = (aa == 0) ? ah0 : ((aa == 1) ? ah1 : ah2);
            const float c1x = acx - aw * 0.5f, c1y = acy - ah * 0.5f;
            const float c2x = acx + aw * 0.5f, c2y = acy + ah * 0.5f;
            const float ltx = fmaxf(x1, c1x), lty = fmaxf(y1, c1y);
            const float rbx = fminf(x2, c2x), rby = fminf(y2, c2y);
            const float wx = fmaxf(rbx - ltx, 0.0f), wy = fmaxf(rby - lty, 0.0f);
            const float inter = wx * wy;
            const float iou = inter / (area1 + aw * ah - inter + 1e-16f);
            if (iou > biou) { biou = iou; ba = aa; }   // strict > keeps first max (jnp.argmax)
        }
        key = ba * HW + gy * W + gx;
        s_key[tid] = key;
        s_iou[tid] = biou;
    }
    __syncthreads();

    // stage 1b: winner resolution + target precompute (lanes 0..31 of wave 0) — no loads
    if (tid < NGT) {
        bool chosen = true;
        for (int m = 0; m < NGT; ++m) {
            if (m == tid) continue;
            if (s_key[m] == key) {
                const float im = s_iou[m];
                if (im > biou || (im == biou && m < tid)) chosen = false;
            }
        }
        if (chosen) {
            const float aw = (ba == 0) ? aw0 : ((ba == 1) ? aw1 : aw2);
            const float ah = (ba == 0) ? ah0 : ((ba == 1) ? ah1 : ah2);
            s_t[tid][0] = (cx - acx) * 0.125f;   // / STRIDES[0] = 8
            s_t[tid][1] = (cy - acy) * 0.125f;
            s_t[tid][2] = logf((x2 - x1) / aw + 1e-16f);
            s_t[tid][3] = logf((y2 - y1) / ah + 1e-16f);
            s_lab[tid]  = lab;
            s_off[tid]  = (unsigned)(((b * NA + ba) * HW + gy * W + gx) * (5 + NCLS));
        } else {
            s_off[tid] = 0xFFFFFFFFu;
        }
        const unsigned long long mm = __ballot(chosen);
        if (tid == 0) s_np = (float)__popcll(mm);
    }
    __syncthreads();

    // stage 2: all 4 waves; wave w handles GTs [w*8, w*8+8).
    // Lane i covers prediction element i (and i+64 when i<21): 2 parallel loads per GT.
    float accO = 0.f, accB = 0.f, accC = 0.f;
    for (int g = wid * 8; g < wid * 8 + 8; ++g) {
        const unsigned off = s_off[g];           // uniform per wave
        if (off == 0xFFFFFFFFu) continue;
        const float* f = pred + off;
        const int glab = s_lab[g];
        const float v0 = f[lane];
        if (lane < 4) {
            const float d = v0 - s_t[g][lane];
            accB += d * d;
        } else if (lane == 4) {
            accO += v0;
        } else {
            accC += softplusf(v0);
            if (lane - 5 == glab) accC -= v0;
        }
        if (lane < 21) {
            const float v1 = f[lane + 64];
            accC += softplusf(v1);
            if (lane + 59 == glab) accC -= v1;
        }
    }

    for (int off = 32; off > 0; off >>= 1) {
        accO += __shfl_down(accO, off);
        accB += __shfl_down(accB, off);
        accC += __shfl_down(accC, off);
    }
    if (lane == 0) { s_red[wid][0] = accO; s_red[wid][1] = accB; s_red[wid][2] = accC; }
    __syncthreads();
    if (tid == 0) {
        float* dst = ws + ASSIGN_OFF + (size_t)aid * 4;
        dst[0] = s_red[0][0] + s_red[1][0] + s_red[2][0] + s_red[3][0];
        dst[1] = s_red[0][1] + s_red[1][1] + s_red[2][1] + s_red[3][1];
        dst[2] = s_red[0][2] + s_red[1][2] + s_red[2][2] + s_red[3][2];
        dst[3] = s_np;
    }
}

__global__ void finalize_kernel(const float* __restrict__ ws, float* __restrict__ out) {
    const int tid = threadIdx.x;
    const int lane = tid & 63, wid = tid >> 6;

    // reduce obj partials into per-level sums (394 entries)
    float a0 = 0.f, a1 = 0.f, a2 = 0.f;
    for (int i = tid; i < OBJ_NB; i += 256) {
        const float v = ws[i];
        if (i < OBJ_B0)       a0 += v;
        else if (i < OBJ_B01) a1 += v;
        else                  a2 += v;
    }
    for (int off = 32; off > 0; off >>= 1) {
        a0 += __shfl_down(a0, off);
        a1 += __shfl_down(a1, off);
        a2 += __shfl_down(a2, off);
    }
    __shared__ float red[4][3];
    if (lane == 0) { red[wid][0] = a0; red[wid][1] = a1; red[wid][2] = a2; }

    // reduce assign partials wave-parallel (wave 1: lane g < 48 owns record g)
    __shared__ float ared[4][NLEV];   // {po, bx, cl, np} x level
    if (wid == 1) {
        float po = 0.f, bx = 0.f, cl = 0.f, np = 0.f;
        int l = 0;
        if (lane < NASSIGN) {
            const float* src = ws + ASSIGN_OFF + (size_t)lane * 4;
            po = src[0]; bx = src[1]; cl = src[2]; np = src[3];
            l = lane % NLEV;
        }
        for (int lv = 0; lv < NLEV; ++lv) {
            float vpo = (l == lv && lane < NASSIGN) ? po : 0.f;
            float vbx = (l == lv && lane < NASSIGN) ? bx : 0.f;
            float vcl = (l == lv && lane < NASSIGN) ? cl : 0.f;
            float vnp = (l == lv && lane < NASSIGN) ? np : 0.f;
            for (int off = 32; off > 0; off >>= 1) {
                vpo += __shfl_down(vpo, off);
                vbx += __shfl_down(vbx, off);
                vcl += __shfl_down(vcl, off);
                vnp += __shfl_down(vnp, off);
            }
            if (lane == 0) { ared[0][lv] = vpo; ared[1][lv] = vbx; ared[2][lv] = vcl; ared[3][lv] = vnp; }
        }
    }
    __syncthreads();

    if (tid == 0) {
        const float BK0 = (float)P0, BK1 = (float)P1, BK2 = (float)P2;
        float tb = 0.f, to = 0.f, tc = 0.f, tot = 0.f;
        for (int l = 0; l < NLEV; ++l) {
            const float BKl = (l == 0) ? BK0 : ((l == 1) ? BK1 : BK2);
            const float sp = red[0][l] + red[1][l] + red[2][l] + red[3][l];
            const float po = ared[0][l], bx = ared[1][l], cl = ared[2][l], np = ared[3][l];
            const float denom = fmaxf(np, 1.0f);
            const float obj_l = (sp - po) / BKl;
            const float box_l = bx / denom;
            const float cls_l = cl / (denom * (float)NCLS);
            if (np > 0.f) { tb += box_l; tc += cls_l; }
            to += obj_l;
            tot += np;
        }
        if (tot > 0.f) { tb /= 3.0f; tc /= 3.0f; } else { tb = 0.f; tc = 0.f; }
        to /= 3.0f;
        out[0] = 0.05f * tb + 1.0f * to + 0.5f * tc;
    }
}

extern "C" void kernel_launch(void* const* d_in, const int* in_sizes, int n_in,
                              void* d_out, int out_size, void* d_ws, size_t ws_size,
                              hipStream_t stream) {
    // defensive pointer mapping by element count (all sizes distinct)
    const float* p[3] = {nullptr, nullptr, nullptr};
    const float* gtb = nullptr;
    const int*   gtl = nullptr;
    for (int i = 0; i < n_in; ++i) {
        switch (in_sizes[i]) {
            case 26112000: p[0] = (const float*)d_in[i]; break;
            case 6528000:  p[1] = (const float*)d_in[i]; break;
            case 1632000:  p[2] = (const float*)d_in[i]; break;
            case 2048:     gtb  = (const float*)d_in[i]; break;
            case 512:      gtl  = (const int*)d_in[i];   break;
            default: break;
        }
    }
    if (!p[0]) p[0] = (const float*)d_in[0];
    if (!p[1]) p[1] = (const float*)d_in[2];
    if (!p[2]) p[2] = (const float*)d_in[4];
    if (!gtb)  gtb  = (const float*)d_in[6];
    if (!gtl)  gtl  = (const int*)d_in[7];

    float* ws = (float*)d_ws;

    fused_kernel<<<NB, 256, 0, stream>>>(p[0], p[1], p[2], gtb, gtl, ws);
    finalize_kernel<<<1, 256, 0, stream>>>(ws, (float*)d_out);
}

// Round 7
// 18.906 us; speedup vs baseline: 3.2096x; 1.2418x over previous
//
#include <hip/hip_runtime.h>
#include <math.h>

#define NLEV 3
#define BATCH 16
#define NGT 32
#define NCLS 80
#define NA 3

// positions per level = B*A*H*W
#define P0 307200
#define P1 76800
#define P2 19200

// obj: 1024 positions per block (256 threads x 4)
#define OBJ_NB0 300            // P0 / 1024
#define OBJ_NB1 75             // P1 / 1024
#define OBJ_NB2 19             // ceil(P2 / 1024)
#define OBJ_NB  (OBJ_NB0 + OBJ_NB1 + OBJ_NB2)   // 394
#define OBJ_B0  OBJ_NB0
#define OBJ_B01 (OBJ_NB0 + OBJ_NB1)             // 375

#define NASSIGN (BATCH * NLEV)  // 48
#define NB (NASSIGN + OBJ_NB)   // 442; assign blocks FIRST (longest dep chain)

// ws layout (floats):
// [0 .. OBJ_NB)            per-obj-block softplus partial sums
// [4096 + aid*4 .. +4)     per-(b,lev) partials: {sum obj_p@pos, sum boxsq, sum cls, npos}
#define ASSIGN_OFF 4096

__device__ __forceinline__ float softplusf(float x) {
    // stable log(1+exp(x)) == max(x,0) + log1p(exp(-|x|))
    return fmaxf(x, 0.0f) + log1pf(expf(-fabsf(x)));
}

__global__ void fused_kernel(const float* __restrict__ p0, const float* __restrict__ p1,
                             const float* __restrict__ p2,
                             const float* __restrict__ gtb, const int* __restrict__ gtl,
                             float* __restrict__ ws) {
    const int blk = blockIdx.x;
    const int tid = threadIdx.x;
    const int wid = tid >> 6, lane = tid & 63;

    __shared__ float wsum[4];
    __shared__ int      s_key[NGT];
    __shared__ float    s_iou[NGT];
    __shared__ unsigned s_off[NGT];      // element offset into pred, 0xFFFFFFFF = not chosen
    __shared__ float    s_t[NGT][4];
    __shared__ int      s_lab[NGT];
    __shared__ float    s_np;
    __shared__ float    s_red[4][3];

    if (blk >= NASSIGN) {
        // ---- obj duty: softplus over obj logits, 4 positions per thread ----
        const int ob = blk - NASSIGN;
        const float* p;
        int base, plim;
        if (ob < OBJ_NB0)      { p = p0; base = ob * 1024;               plim = P0; }
        else if (ob < OBJ_B01) { p = p1; base = (ob - OBJ_NB0) * 1024;   plim = P1; }
        else                   { p = p2; base = (ob - OBJ_B01) * 1024;   plim = P2; }

        float v = 0.0f;
        #pragma unroll
        for (int k = 0; k < 4; ++k) {
            const int pos = base + k * 256 + tid;
            if (pos < plim) v += softplusf(p[(size_t)pos * (5 + NCLS) + 4]);
        }
        for (int off = 32; off > 0; off >>= 1) v += __shfl_down(v, off);
        if (lane == 0) wsum[wid] = v;
        __syncthreads();
        if (tid == 0) ws[ob] = wsum[0] + wsum[1] + wsum[2] + wsum[3];
        return;
    }

    // ---- assign duty: one block per (b, lev); anchors computed analytically ----
    const int aid = blk;
    const int lev = aid % NLEV;
    const int b   = aid / NLEV;

    // block-uniform level params via select chains (no runtime-indexed arrays -> no scratch)
    const float* pred = (lev == 0) ? p0 : ((lev == 1) ? p1 : p2);
    const int   W      = (lev == 0) ? 80 : ((lev == 1) ? 40 : 20);
    const float stride = (lev == 0) ? 8.0f : ((lev == 1) ? 16.0f : 32.0f);
    const int H = W;
    const int HW = H * W;
    // anchor sizes per level (reference ANCHOR_SIZES), compile-time constants selected by lev
    const float aw0 = (lev == 0) ? 12.f  : ((lev == 1) ? 36.f : 142.f);
    const float ah0 = (lev == 0) ? 16.f  : ((lev == 1) ? 75.f : 110.f);
    const float aw1 = (lev == 0) ? 19.f  : ((lev == 1) ? 76.f : 192.f);
    const float ah1 = (lev == 0) ? 36.f  : ((lev == 1) ? 55.f : 243.f);
    const float aw2 = (lev == 0) ? 40.f  : ((lev == 1) ? 72.f : 459.f);
    const float ah2 = (lev == 0) ? 28.f  : ((lev == 1) ? 146.f : 401.f);

    // stage 1a: per-GT best anchor (lanes 0..31 of wave 0) — one coalesced float4 load, rest ALU
    float x1 = 0.f, y1 = 0.f, x2 = 0.f, y2 = 0.f, cx = 0.f, cy = 0.f;
    float acx = 0.f, acy = 0.f;
    float biou = -1.0f;
    int ba = 0, gx = 0, gy = 0, key = -1, lab = 0;

    if (tid < NGT) {
        const float4 g = ((const float4*)gtb)[b * NGT + tid];
        lab = gtl[b * NGT + tid];          // independent load, issues in parallel
        x1 = g.x; y1 = g.y; x2 = g.z; y2 = g.w;
        cx = (x1 + x2) * 0.5f;
        cy = (y1 + y2) * 0.5f;
        gx = (int)(cx / stride); gx = gx < 0 ? 0 : (gx > W - 1 ? W - 1 : gx);
        gy = (int)(cy / stride); gy = gy < 0 ? 0 : (gy > H - 1 ? H - 1 : gy);
        acx = ((float)gx + 0.5f) * stride;   // grid centers exact in f32 (stride pow2)
        acy = ((float)gy + 0.5f) * stride;
        const float area1 = (x2 - x1) * (y2 - y1);
        #pragma unroll
        for (int aa = 0; aa < NA; ++aa) {
            const float aw = (aa == 0) ? aw0 : ((aa == 1) ? aw1 : aw2);
            const float ah = (aa == 0) ? ah0 : ((aa == 1) ? ah1 : ah2);
            const float c1x = acx - aw * 0.5f, c1y = acy - ah * 0.5f;
            const float c2x = acx + aw * 0.5f, c2y = acy + ah * 0.5f;
            const float ltx = fmaxf(x1, c1x), lty = fmaxf(y1, c1y);
            const float rbx = fminf(x2, c2x), rby = fminf(y2, c2y);
            const float wx = fmaxf(rbx - ltx, 0.0f), wy = fmaxf(rby - lty, 0.0f);
            const float inter = wx * wy;
            const float iou = inter / (area1 + aw * ah - inter + 1e-16f);
            if (iou > biou) { biou = iou; ba = aa; }   // strict > keeps first max (jnp.argmax)
        }
        key = ba * HW + gy * W + gx;
        s_key[tid] = key;
        s_iou[tid] = biou;
    }
    __syncthreads();

    // stage 1b: winner resolution + target precompute (lanes 0..31 of wave 0) — no loads
    if (tid < NGT) {
        bool chosen = true;
        for (int m = 0; m < NGT; ++m) {
            if (m == tid) continue;
            if (s_key[m] == key) {
                const float im = s_iou[m];
                if (im > biou || (im == biou && m < tid)) chosen = false;
            }
        }
        if (chosen) {
            const float aw = (ba == 0) ? aw0 : ((ba == 1) ? aw1 : aw2);
            const float ah = (ba == 0) ? ah0 : ((ba == 1) ? ah1 : ah2);
            s_t[tid][0] = (cx - acx) * 0.125f;   // / STRIDES[0] = 8
            s_t[tid][1] = (cy - acy) * 0.125f;
            s_t[tid][2] = logf((x2 - x1) / aw + 1e-16f);
            s_t[tid][3] = logf((y2 - y1) / ah + 1e-16f);
            s_lab[tid]  = lab;
            s_off[tid]  = (unsigned)(((b * NA + ba) * HW + gy * W + gx) * (5 + NCLS));
        } else {
            // initialize so predicated stage-2 math stays finite (no NaN x 0 hazards)
            s_t[tid][0] = 0.f; s_t[tid][1] = 0.f; s_t[tid][2] = 0.f; s_t[tid][3] = 0.f;
            s_lab[tid] = -1;
            s_off[tid] = 0xFFFFFFFFu;
        }
        const unsigned long long mm = __ballot(chosen);
        if (tid == 0) s_np = (float)__popcll(mm);
    }
    __syncthreads();

    // stage 2: wave w handles GTs [w*8, w*8+8). BRANCH-FREE: unconditional loads
    // (dummy offset 0 for non-chosen -> always-valid memory), predicated accumulate.
    // Straight-line body lets the compiler batch all 16 global loads behind one wait.
    unsigned offs[8];
    int      labs[8];
    #pragma unroll
    for (int k = 0; k < 8; ++k) {
        offs[k] = s_off[wid * 8 + k];
        labs[k] = s_lab[wid * 8 + k];
    }

    float accO = 0.f, accB = 0.f, accC = 0.f;
    #pragma unroll
    for (int k = 0; k < 8; ++k) {
        const int g = wid * 8 + k;
        const bool ok = (offs[k] != 0xFFFFFFFFu);
        const float* f = pred + (ok ? offs[k] : 0u);
        const int idx1 = (lane < 21) ? (lane + 64) : 0;   // in-bounds for all lanes
        const float v0 = f[lane];
        const float v1 = f[idx1];
        const float tv = s_t[g][lane & 3];
        const int glab = labs[k];

        const float d = v0 - tv;
        accB += (ok && lane < 4)  ? d * d : 0.0f;
        accO += (ok && lane == 4) ? v0    : 0.0f;
        const float c0 = softplusf(v0) - ((lane - 5 == glab) ? v0 : 0.0f);
        accC += (ok && lane >= 5) ? c0 : 0.0f;
        const float c1 = softplusf(v1) - ((lane + 59 == glab) ? v1 : 0.0f);
        accC += (ok && lane < 21) ? c1 : 0.0f;
    }

    for (int off = 32; off > 0; off >>= 1) {
        accO += __shfl_down(accO, off);
        accB += __shfl_down(accB, off);
        accC += __shfl_down(accC, off);
    }
    if (lane == 0) { s_red[wid][0] = accO; s_red[wid][1] = accB; s_red[wid][2] = accC; }
    __syncthreads();
    if (tid == 0) {
        float* dst = ws + ASSIGN_OFF + (size_t)aid * 4;
        dst[0] = s_red[0][0] + s_red[1][0] + s_red[2][0] + s_red[3][0];
        dst[1] = s_red[0][1] + s_red[1][1] + s_red[2][1] + s_red[3][1];
        dst[2] = s_red[0][2] + s_red[1][2] + s_red[2][2] + s_red[3][2];
        dst[3] = s_np;
    }
}

__global__ void finalize_kernel(const float* __restrict__ ws, float* __restrict__ out) {
    const int tid = threadIdx.x;
    const int lane = tid & 63, wid = tid >> 6;

    // reduce obj partials into per-level sums (394 entries)
    float a0 = 0.f, a1 = 0.f, a2 = 0.f;
    for (int i = tid; i < OBJ_NB; i += 256) {
        const float v = ws[i];
        if (i < OBJ_B0)       a0 += v;
        else if (i < OBJ_B01) a1 += v;
        else                  a2 += v;
    }
    for (int off = 32; off > 0; off >>= 1) {
        a0 += __shfl_down(a0, off);
        a1 += __shfl_down(a1, off);
        a2 += __shfl_down(a2, off);
    }
    __shared__ float red[4][3];
    if (lane == 0) { red[wid][0] = a0; red[wid][1] = a1; red[wid][2] = a2; }

    // reduce assign partials wave-parallel (wave 1: lane g < 48 owns record g)
    __shared__ float ared[4][NLEV];   // {po, bx, cl, np} x level
    if (wid == 1) {
        float po = 0.f, bx = 0.f, cl = 0.f, np = 0.f;
        int l = 0;
        if (lane < NASSIGN) {
            const float* src = ws + ASSIGN_OFF + (size_t)lane * 4;
            po = src[0]; bx = src[1]; cl = src[2]; np = src[3];
            l = lane % NLEV;
        }
        for (int lv = 0; lv < NLEV; ++lv) {
            float vpo = (l == lv && lane < NASSIGN) ? po : 0.f;
            float vbx = (l == lv && lane < NASSIGN) ? bx : 0.f;
            float vcl = (l == lv && lane < NASSIGN) ? cl : 0.f;
            float vnp = (l == lv && lane < NASSIGN) ? np : 0.f;
            for (int off = 32; off > 0; off >>= 1) {
                vpo += __shfl_down(vpo, off);
                vbx += __shfl_down(vbx, off);
                vcl += __shfl_down(vcl, off);
                vnp += __shfl_down(vnp, off);
            }
            if (lane == 0) { ared[0][lv] = vpo; ared[1][lv] = vbx; ared[2][lv] = vcl; ared[3][lv] = vnp; }
        }
    }
    __syncthreads();

    if (tid == 0) {
        const float BK0 = (float)P0, BK1 = (float)P1, BK2 = (float)P2;
        float tb = 0.f, to = 0.f, tc = 0.f, tot = 0.f;
        for (int l = 0; l < NLEV; ++l) {
            const float BKl = (l == 0) ? BK0 : ((l == 1) ? BK1 : BK2);
            const float sp = red[0][l] + red[1][l] + red[2][l] + red[3][l];
            const float po = ared[0][l], bx = ared[1][l], cl = ared[2][l], np = ared[3][l];
            const float denom = fmaxf(np, 1.0f);
            const float obj_l = (sp - po) / BKl;
            const float box_l = bx / denom;
            const float cls_l = cl / (denom * (float)NCLS);
            if (np > 0.f) { tb += box_l; tc += cls_l; }
            to += obj_l;
            tot += np;
        }
        if (tot > 0.f) { tb /= 3.0f; tc /= 3.0f; } else { tb = 0.f; tc = 0.f; }
        to /= 3.0f;
        out[0] = 0.05f * tb + 1.0f * to + 0.5f * tc;
    }
}

extern "C" void kernel_launch(void* const* d_in, const int* in_sizes, int n_in,
                              void* d_out, int out_size, void* d_ws, size_t ws_size,
                              hipStream_t stream) {
    // defensive pointer mapping by element count (all sizes distinct)
    const float* p[3] = {nullptr, nullptr, nullptr};
    const float* gtb = nullptr;
    const int*   gtl = nullptr;
    for (int i = 0; i < n_in; ++i) {
        switch (in_sizes[i]) {
            case 26112000: p[0] = (const float*)d_in[i]; break;
            case 6528000:  p[1] = (const float*)d_in[i]; break;
            case 1632000:  p[2] = (const float*)d_in[i]; break;
            case 2048:     gtb  = (const float*)d_in[i]; break;
            case 512:      gtl  = (const int*)d_in[i];   break;
            default: break;
        }
    }
    if (!p[0]) p[0] = (const float*)d_in[0];
    if (!p[1]) p[1] = (const float*)d_in[2];
    if (!p[2]) p[2] = (const float*)d_in[4];
    if (!gtb)  gtb  = (const float*)d_in[6];
    if (!gtl)  gtl  = (const int*)d_in[7];

    float* ws = (float*)d_ws;

    fused_kernel<<<NB, 256, 0, stream>>>(p[0], p[1], p[2], gtb, gtl, ws);
    finalize_kernel<<<1, 256, 0, stream>>>(ws, (float*)d_out);
}